// Round 5
// baseline (121.864 us; speedup 1.0000x reference)
//
#include <hip/hip_runtime.h>

// Problem constants (from reference setup_inputs)
#define BB 4
#define CC 12
#define DD 8
#define HG 16
#define WG 16
#define HH 1024
#define WW 1024

// Native 4-float vector (clang ext vector) — legal operand for
// __builtin_nontemporal_load/store, unlike HIP_vector_type<float,4>.
typedef float vf4 __attribute__((ext_vector_type(4)));

// bf16 slab: per row, S[x * XS + z*CC + c] (ushort index).
// XS = 8*12 + 8 pad ushorts = 104 -> byte x-stride 208, z-stride 24:
//   dword bank = (x*52 + z*6 + k) % 32 — x*52%32 and z*6%32 both hit
//   distinct residues, so guide-random z spreads across banks.
// Cell (24 B) is read as 3x ds_read_b64 (8B-aligned: 208%8==0, 24%8==0).
#define XS 104
#define ROWS 4   // rows per block; 4-aligned groups never straddle an fy band
                 // (fy increments at h = 32 + 64k, which is 0 mod 4)

__device__ __forceinline__ unsigned int f32_to_bf16_rne(float f) {
    unsigned int u = __float_as_uint(f);
    return (u + 0x7FFFu + ((u >> 16) & 1u)) >> 16;   // round-nearest-even
}

__global__ __launch_bounds__(256) void slice_apply(
    const float* __restrict__ grid,   // [B,C,D,HG,WG]
    const float* __restrict__ guide,  // [B,H,W]
    const float* __restrict__ img,    // [B,3,H,W]
    float* __restrict__ out)          // [B,3,H,W]
{
    __shared__ unsigned short Sh[ROWS * WG * XS];  // 4 * 3328 B = 13312 B

    const int blk = blockIdx.x;
    const int b  = blk >> 8;                 // HH/ROWS = 256 row-groups per batch
    const int h0 = (blk & 255) * ROWS;

    // y-cell pair shared by all ROWS rows of this block
    const float gy0 = (h0 + 0.5f) * ((float)HG / (float)HH);
    const float fy  = floorf(gy0 - 0.5f);
    const int   iy0 = max(0, min(HG - 1, (int)fy));
    const int   iy1 = max(0, min(HG - 1, (int)fy + 1));

    float wy1r[ROWS];
    #pragma unroll
    for (int r = 0; r < ROWS; ++r) {
        const float gy = (h0 + r + 0.5f) * ((float)HG / (float)HH);
        wy1r[r] = gy - 0.5f - fy;           // ty in [0,1)
    }

    // Stage: load the two raw y-slices once (channel PAIRS so two bf16 pack
    // into one dword LDS write), fold into ROWS per-row bf16 slabs.
    // 768 iterations: flat index (cpair, z, x), x fastest for coalescing.
    for (int j = threadIdx.x; j < (CC / 2) * DD * WG; j += 256) {
        const int x  = j & 15;
        const int z  = (j >> 4) & 7;
        const int cp = j >> 7;               // 0..5
        const size_t be = ((size_t)(b * CC + 2 * cp)     * DD + z) * (HG * WG);
        const size_t bo = ((size_t)(b * CC + 2 * cp + 1) * DD + z) * (HG * WG);
        const float e0 = grid[be + iy0 * WG + x];
        const float e1 = grid[be + iy1 * WG + x];
        const float o0 = grid[bo + iy0 * WG + x];
        const float o1 = grid[bo + iy1 * WG + x];
        const int so = x * XS + z * CC + 2 * cp;   // even -> dword-aligned
        #pragma unroll
        for (int r = 0; r < ROWS; ++r) {
            const float ty = wy1r[r];
            const float ve = e0 + ty * (e1 - e0);
            const float vo = o0 + ty * (o1 - o0);
            const unsigned int pk = f32_to_bf16_rne(ve) | (f32_to_bf16_rne(vo) << 16);
            *reinterpret_cast<unsigned int*>(&Sh[r * (WG * XS) + so]) = pk;
        }
    }
    __syncthreads();

    const int w0 = threadIdx.x * 4;

    // x cell pair is uniform across the 4 pixels of this thread
    const float scale = (float)WG / (float)WW;       // 1/64
    const float gx0 = (w0 + 0.5f) * scale;
    const float fx  = floorf(gx0 - 0.5f);
    const float tx0 = gx0 - 0.5f - fx;
    const int   ix0 = max(0, min(WG - 1, (int)fx));
    const int   ix1 = max(0, min(WG - 1, (int)fx + 1));

    #pragma unroll
    for (int r = 0; r < ROWS; ++r) {
        const int h = h0 + r;
        const unsigned short* Sr  = Sh + r * (WG * XS);
        const unsigned short* Sx0 = Sr + ix0 * XS;
        const unsigned short* Sx1 = Sr + ix1 * XS;

        const size_t pix = ((size_t)b * HH + h) * WW + w0;
        const vf4 g4 = *reinterpret_cast<const vf4*>(guide + pix);
        const float* ib = img + (((size_t)b * 3) * HH + h) * WW + w0;
        const vf4 i0 = __builtin_nontemporal_load(reinterpret_cast<const vf4*>(ib));
        const vf4 i1 = __builtin_nontemporal_load(reinterpret_cast<const vf4*>(ib + (size_t)HH * WW));
        const vf4 i2 = __builtin_nontemporal_load(reinterpret_cast<const vf4*>(ib + (size_t)2 * HH * WW));

        vf4 o0, o1, o2;

        #pragma unroll
        for (int p = 0; p < 4; ++p) {
            const float tx  = tx0 + (float)p * scale;
            const float wx0 = 1.0f - tx, wx1 = tx;

            const float gz  = g4[p] * (float)DD;
            const float fz  = floorf(gz - 0.5f);
            const float tz  = gz - 0.5f - fz;
            const int   iz0 = max(0, min(DD - 1, (int)fz));
            const int   iz1 = max(0, min(DD - 1, (int)fz + 1));
            const float wz0 = 1.0f - tz, wz1 = tz;

            const float w00 = wz0 * wx0, w01 = wz0 * wx1;
            const float w10 = wz1 * wx0, w11 = wz1 * wx1;

            float acc[12];
            #pragma unroll
            for (int k = 0; k < 12; ++k) acc[k] = 0.0f;

            auto accum = [&](const unsigned short* P, float w) {
                const uint2 q0 = *reinterpret_cast<const uint2*>(P);      // ch 0..3
                const uint2 q1 = *reinterpret_cast<const uint2*>(P + 4);  // ch 4..7
                const uint2 q2 = *reinterpret_cast<const uint2*>(P + 8);  // ch 8..11
                const unsigned int d[6] = {q0.x, q0.y, q1.x, q1.y, q2.x, q2.y};
                #pragma unroll
                for (int k = 0; k < 6; ++k) {
                    acc[2 * k]     += w * __uint_as_float(d[k] << 16);
                    acc[2 * k + 1] += w * __uint_as_float(d[k] & 0xFFFF0000u);
                }
            };
            accum(Sx0 + iz0 * CC, w00);
            accum(Sx1 + iz0 * CC, w01);
            accum(Sx0 + iz1 * CC, w10);
            accum(Sx1 + iz1 * CC, w11);

            const float im0 = i0[p];
            const float im1 = i1[p];
            const float im2 = i2[p];

            o0[p] = acc[0] * im0 + acc[1] * im1 + acc[2]  * im2 + acc[3];
            o1[p] = acc[4] * im0 + acc[5] * im1 + acc[6]  * im2 + acc[7];
            o2[p] = acc[8] * im0 + acc[9] * im1 + acc[10] * im2 + acc[11];
        }

        float* ob = out + (((size_t)b * 3) * HH + h) * WW + w0;
        __builtin_nontemporal_store(o0, reinterpret_cast<vf4*>(ob));
        __builtin_nontemporal_store(o1, reinterpret_cast<vf4*>(ob + (size_t)HH * WW));
        __builtin_nontemporal_store(o2, reinterpret_cast<vf4*>(ob + (size_t)2 * HH * WW));
    }
}

extern "C" void kernel_launch(void* const* d_in, const int* in_sizes, int n_in,
                              void* d_out, int out_size, void* d_ws, size_t ws_size,
                              hipStream_t stream) {
    const float* grid  = (const float*)d_in[0];
    const float* guide = (const float*)d_in[1];
    const float* image = (const float*)d_in[2];
    float* out = (float*)d_out;

    const int nblocks = BB * HH / ROWS;  // 1024 blocks, 4 rows each
    slice_apply<<<nblocks, 256, 0, stream>>>(grid, guide, image, out);
}